// Round 13
// baseline (383.060 us; speedup 1.0000x reference)
//
#include <hip/hip_runtime.h>

#define NN 50000
#define NE 800000
#define D 64
#define SLICE 64                        // dst nodes per slice block
#define NBLK 782                        // ceil(NN/SLICE)
#define NSHARD 8                        // shards per bucket = waves per slice block
#define SCAP 256                        // per-shard capacity (mean ~128, 11 sigma), mult of 64
#define CSTRIDE 16                      // cursor padding: 64 B
#define UVNODES 128                     // nodes per uv block (32 per wave)
#define UVBLK 391                       // ceil(NN/UVNODES)
#define BINBLK 782                      // ceil((NE/4)/256)
#define SCRTOT 2304                     // sorted-list capacity (max 2240 + tail)
#define NINF (-__builtin_inff())

typedef int i32x4 __attribute__((ext_vector_type(4)));
typedef float f32x4 __attribute__((ext_vector_type(4)));

__device__ __forceinline__ float b2f(unsigned short h) {
    unsigned int u = ((unsigned int)h) << 16;
    return __builtin_bit_cast(float, u);
}
__device__ __forceinline__ unsigned short f2bf(float f) {
    unsigned int u = __builtin_bit_cast(unsigned int, f);
    u = (u + 0x7fffu + ((u >> 16) & 1u)) >> 16;
    return (unsigned short)u;
}

// ---------------------------------------------------------------------------
// pre_fused: blocks [0, UVBLK) compute u,v; blocks [UVBLK, ..) bin edges.
// NEW: all 8 groups' x prefetched into registers upfront (32 independent
// global loads) -> one latency exposure instead of one per group.
// ---------------------------------------------------------------------------
__global__ __launch_bounds__(256) void pre_fused(
    const float* __restrict__ x,
    const int* __restrict__ ei,
    const float* __restrict__ W_edge,
    const float* __restrict__ b_edge,
    unsigned short* __restrict__ u,
    unsigned short* __restrict__ v,
    unsigned int* __restrict__ bins,
    unsigned int* __restrict__ cursor)
{
    __shared__ float Wu[D * D];        // Wtop - Wbot   (16 KB)
    __shared__ float Wv[D * D];        // Wbot          (16 KB)
    __shared__ float xs[4][D][4];      // [wave][k][node] (4 KB)

    const int tid  = threadIdx.x;
    const int lane = tid & 63;
    const int wid  = tid >> 6;

    if (blockIdx.x < UVBLK) {
        for (int i = tid; i < D * D; i += 256) {
            float wt = W_edge[i], wb = W_edge[D * D + i];
            Wu[i] = wt - wb;
            Wv[i] = wb;
        }

        // upfront x prefetch: 32 independent loads (clamped base, stores guarded)
        float xr[8][4];
#pragma unroll
        for (int g = 0; g < 8; ++g) {
            int n0 = blockIdx.x * UVNODES + wid * 32 + g * 4;
            int n0c = (n0 <= NN - 4) ? n0 : (NN - 4);
#pragma unroll
            for (int j = 0; j < 4; ++j)
                xr[g][j] = x[(size_t)(n0c + j) * D + lane];
        }
        __syncthreads();

        const float be = b_edge[lane];
#pragma unroll 1
        for (int g = 0; g < 8; ++g) {
            const int n0 = blockIdx.x * UVNODES + wid * 32 + g * 4;
#pragma unroll
            for (int j = 0; j < 4; ++j)
                xs[wid][lane][j] = xr[g][j];
            float au0 = be, au1 = be, au2 = be, au3 = be;
            float av0 = 0.f, av1 = 0.f, av2 = 0.f, av3 = 0.f;
#pragma unroll
            for (int k = 0; k < D; ++k) {
                f32x4 x4 = *(const f32x4*)&xs[wid][k][0];   // wave-uniform
                float wu = Wu[k * D + lane];
                float wv = Wv[k * D + lane];
                au0 += x4[0] * wu;  av0 += x4[0] * wv;
                au1 += x4[1] * wu;  av1 += x4[1] * wv;
                au2 += x4[2] * wu;  av2 += x4[2] * wv;
                au3 += x4[3] * wu;  av3 += x4[3] * wv;
            }
            if (n0 < NN) {   // n0 % 4 == 0 and NN % 4 == 0 -> all 4 valid
                u[(size_t)(n0 + 0) * D + lane] = f2bf(au0);
                u[(size_t)(n0 + 1) * D + lane] = f2bf(au1);
                u[(size_t)(n0 + 2) * D + lane] = f2bf(au2);
                u[(size_t)(n0 + 3) * D + lane] = f2bf(au3);
                v[(size_t)(n0 + 0) * D + lane] = f2bf(av0);
                v[(size_t)(n0 + 1) * D + lane] = f2bf(av1);
                v[(size_t)(n0 + 2) * D + lane] = f2bf(av2);
                v[(size_t)(n0 + 3) * D + lane] = f2bf(av3);
            }
        }
    } else {
        const int bb = blockIdx.x - UVBLK;
        if (bb == 0 && tid < 64)
            v[(size_t)NN * D + tid] = 0xFF80;           // sentinel row = -inf
        const int gtid = bb * 256 + tid;
        if (gtid * 4 < NE) {
            const int e0 = gtid * 4;
            const unsigned int sh = (unsigned int)(gtid & (NSHARD - 1));
            i32x4 s4 = *(const i32x4*)(ei + e0);
            i32x4 d4 = *(const i32x4*)(ei + NE + e0);
#pragma unroll
            for (int j = 0; j < 4; ++j) {
                unsigned int se = (unsigned int)s4[j];
                unsigned int de = (unsigned int)d4[j];
                unsigned int b  = (de >> 6) * NSHARD + sh;
                unsigned int pos = atomicAdd(&cursor[b * CSTRIDE], 1u);
                if (pos < SCAP)
                    bins[(size_t)b * SCAP + pos] = (se << 6) | (de & 63u);
            }
        }
    }
}

// ---------------------------------------------------------------------------
// slice: block owns dst rows [base, base+64). 512 threads = 8 waves.
//   CSR build (as r12), then:
//   aggregation: 2 rows interleaved per unrolled pair -> 8 independent
//     gathers in flight; tails masked (cndmask -inf), garbage idx clamped
//     to sentinel row NN. Results in aggr[8] (all-static indexing).
//   epilogue: 4-row vectorized GEMM — stage 4 rows' x in LDS; per k:
//     1 ds_read_b32 (wres) + 1 uniform f32x4 + 4 FMA. No readlanes.
// LDS: 16K wres + 8K xsE + 9.2K sorted + 0.8K counters = 34 KB.
// ---------------------------------------------------------------------------
__global__ __launch_bounds__(512) void slice_kernel(
    const float* __restrict__ x,
    const float* __restrict__ W_res,
    const float* __restrict__ b_res,
    const unsigned short* __restrict__ u,
    const unsigned short* __restrict__ v,
    const unsigned int* __restrict__ bins,
    const unsigned int* __restrict__ cursor,
    float* __restrict__ out)
{
    __shared__ float wres[D * D];      // 16 KB
    __shared__ float xsE[8][D][4];     // 8 KB epilogue x staging
    __shared__ int sorted[SCRTOT];     // 9.2 KB (src ids, CSR by row)
    __shared__ int cntL[64], ofsL[64], fillL[64];

    const int tid  = threadIdx.x;
    const int lane = tid & 63;
    const int wid  = tid >> 6;                 // 0..7
    const int base = blockIdx.x * SLICE;

    for (int i = tid; i < D * D; i += 512) wres[i] = W_res[i];
    if (tid < 64) { cntL[tid] = 0; fillL[tid] = 0; }
    __syncthreads();

    // ---- CSR build: histogram own shard (no-return ds_add) ----
    const unsigned int cidx = (unsigned int)blockIdx.x * NSHARD + wid;
    unsigned int cntS = cursor[cidx * CSTRIDE];
    if (cntS > SCAP) cntS = SCAP;
    const unsigned int* __restrict__ eb = bins + (size_t)cidx * SCAP;
    for (unsigned int i0 = lane; i0 < cntS; i0 += 64)
        atomicAdd(&cntL[eb[i0] & 63u], 1);
    __syncthreads();

    // ---- exclusive prefix scan of x4-rounded counts (wave 0) ----
    if (wid == 0) {
        int a = (cntL[lane] + 3) & ~3;
        int s = a;
#pragma unroll
        for (int off = 1; off < 64; off <<= 1) {
            int t = __shfl_up(s, off);
            if (lane >= off) s += t;
        }
        ofsL[lane] = s - a;
    }
    __syncthreads();

    // ---- scatter into CSR ----
    for (unsigned int i0 = lane; i0 < cntS; i0 += 64) {
        unsigned int e = eb[i0];
        int dl = (int)(e & 63u);
        int pos = ofsL[dl] + atomicAdd(&fillL[dl], 1);
        sorted[pos] = (int)(e >> 6);
    }
    __syncthreads();

    // ---- pad lists to x4 with sentinel (+4 tail for prefetch overread) ----
    if (tid < 64) {
        int c = cntL[tid], o = ofsL[tid];
        int a = (c + 3) & ~3;
        for (int j = c; j < a; ++j) sorted[o + j] = NN;
        if (tid == 63)
            for (int t = 0; t < 4; ++t) sorted[o + a + t] = NN;
    }
    __syncthreads();

    // ---- aggregation: 2-row interleaved, 8 gathers in flight ----
    float aggr[8];
#pragma unroll
    for (int p = 0; p < 4; ++p) {
        const int r0 = wid * 8 + 2 * p, r1 = r0 + 1;
        const int nc0 = (base + r0 < NN) ? (base + r0) : (NN - 1);
        const int nc1 = (base + r1 < NN) ? (base + r1) : (NN - 1);
        const float ur0 = b2f(u[(size_t)nc0 * D + lane]);
        const float ur1 = b2f(u[(size_t)nc1 * D + lane]);
        const int o0 = ofsL[r0], a0 = (cntL[r0] + 3) & ~3;
        const int o1 = ofsL[r1], a1 = (cntL[r1] + 3) & ~3;
        const int amax = (a0 > a1) ? a0 : a1;
        float m0 = NINF, m1 = NINF;
        i32x4 idx0 = *(const i32x4*)&sorted[o0];
        i32x4 idx1 = *(const i32x4*)&sorted[o1];
        for (int j = 0; j < amax; j += 4) {
            i32x4 nx0 = *(const i32x4*)&sorted[o0 + j + 4];
            i32x4 nx1 = *(const i32x4*)&sorted[o1 + j + 4];
#pragma unroll
            for (int t = 0; t < 4; ++t) {
                unsigned int s0 = (unsigned int)idx0[t]; if (s0 > NN) s0 = NN;
                unsigned int s1 = (unsigned int)idx1[t]; if (s1 > NN) s1 = NN;
                float w0 = b2f(v[(size_t)s0 * D + lane]);
                float w1 = b2f(v[(size_t)s1 * D + lane]);
                m0 = fmaxf(m0, (j + t < a0) ? w0 : NINF);
                m1 = fmaxf(m1, (j + t < a1) ? w1 : NINF);
            }
            idx0 = nx0; idx1 = nx1;
        }
        aggr[2 * p]     = fmaxf(0.f, ur0 + m0);   // empty -> -inf -> 0
        aggr[2 * p + 1] = fmaxf(0.f, ur1 + m1);
    }

    // ---- epilogue: 4-row vectorized residual GEMM ----
    const float br = b_res[lane];
#pragma unroll
    for (int g = 0; g < 2; ++g) {
        const int n0 = base + wid * 8 + g * 4;
        const int n0c = (n0 <= NN - 4) ? n0 : (NN - 4);
#pragma unroll
        for (int j = 0; j < 4; ++j)
            xsE[wid][lane][j] = x[(size_t)(n0c + j) * D + lane];
        float s0 = br, s1 = br, s2 = br, s3 = br;
#pragma unroll
        for (int k = 0; k < D; ++k) {
            f32x4 x4 = *(const f32x4*)&xsE[wid][k][0];   // wave-uniform
            float wr = wres[k * D + lane];
            s0 += x4[0] * wr;
            s1 += x4[1] * wr;
            s2 += x4[2] * wr;
            s3 += x4[3] * wr;
        }
        if (n0 + 0 < NN) out[(size_t)(n0 + 0) * D + lane] = aggr[g * 4 + 0] + s0;
        if (n0 + 1 < NN) out[(size_t)(n0 + 1) * D + lane] = aggr[g * 4 + 1] + s1;
        if (n0 + 2 < NN) out[(size_t)(n0 + 2) * D + lane] = aggr[g * 4 + 2] + s2;
        if (n0 + 3 < NN) out[(size_t)(n0 + 3) * D + lane] = aggr[g * 4 + 3] + s3;
    }
}

extern "C" void kernel_launch(void* const* d_in, const int* in_sizes, int n_in,
                              void* d_out, int out_size, void* d_ws, size_t ws_size,
                              hipStream_t stream) {
    const float* x      = (const float*)d_in[0];
    const int*   ei     = (const int*)d_in[1];
    const float* W_edge = (const float*)d_in[2];
    const float* b_edge = (const float*)d_in[3];
    const float* W_res  = (const float*)d_in[4];
    const float* b_res  = (const float*)d_in[5];
    float* out = (float*)d_out;

    // ws: cursor u32 (~512KB) | bins u32[NBLK*NSHARD*SCAP] (6.4MB)
    //     | u bf16[NN*D] (6.4MB) | v bf16[(NN+1)*D] (6.4MB + sentinel row)
    unsigned int*   cursor = (unsigned int*)d_ws;
    unsigned int*   bins   = (unsigned int*)((char*)d_ws + (1u << 19));
    unsigned short* uu     = (unsigned short*)((char*)d_ws + (1u << 19)
                              + (size_t)NBLK * NSHARD * SCAP * 4);
    unsigned short* vv     = uu + (size_t)NN * D;

    hipMemsetAsync(cursor, 0, NBLK * NSHARD * CSTRIDE * sizeof(unsigned int), stream);
    pre_fused<<<UVBLK + BINBLK, 256, 0, stream>>>(x, ei, W_edge, b_edge, uu, vv, bins, cursor);
    slice_kernel<<<NBLK, 512, 0, stream>>>(x, W_res, b_res, uu, vv, bins, cursor, out);
}

// Round 14
// 122.075 us; speedup vs baseline: 3.1379x; 3.1379x over previous
//
#include <hip/hip_runtime.h>

#define NN 50000
#define NE 800000
#define D 64
#define SLICE 64                        // dst nodes per slice block
#define NBLK 782                        // ceil(NN/SLICE)
#define NSHARD 8                        // shards per bucket = waves per slice block
#define SCAP 256                        // per-shard capacity (mean ~128, 11 sigma), mult of 64
#define CSTRIDE 16                      // cursor padding: 64 B
#define UVNODES 128                     // nodes per uv block (32 per wave)
#define UVBLK 391                       // ceil(NN/UVNODES)
#define BINBLK 782                      // ceil((NE/4)/256)
#define SCRTOT 2304                     // sorted-list capacity (max 2240 + tail)

typedef int i32x4 __attribute__((ext_vector_type(4)));
typedef float f32x4 __attribute__((ext_vector_type(4)));

__device__ __forceinline__ float b2f(unsigned short h) {
    unsigned int u = ((unsigned int)h) << 16;
    return __builtin_bit_cast(float, u);
}
__device__ __forceinline__ unsigned short f2bf(float f) {
    unsigned int u = __builtin_bit_cast(unsigned int, f);
    u = (u + 0x7fffu + ((u >> 16) & 1u)) >> 16;
    return (unsigned short)u;
}

// ---------------------------------------------------------------------------
// pre_fused (round-13 version, measured ~44 us): blocks [0, UVBLK) compute
// u,v with upfront register prefetch of all 8 groups' x (32 independent
// global loads -> one latency exposure); blocks [UVBLK, ..) bin edges.
// ---------------------------------------------------------------------------
__global__ __launch_bounds__(256) void pre_fused(
    const float* __restrict__ x,
    const int* __restrict__ ei,
    const float* __restrict__ W_edge,
    const float* __restrict__ b_edge,
    unsigned short* __restrict__ u,
    unsigned short* __restrict__ v,
    unsigned int* __restrict__ bins,
    unsigned int* __restrict__ cursor)
{
    __shared__ float Wu[D * D];        // Wtop - Wbot   (16 KB)
    __shared__ float Wv[D * D];        // Wbot          (16 KB)
    __shared__ float xs[4][D][4];      // [wave][k][node] (4 KB)

    const int tid  = threadIdx.x;
    const int lane = tid & 63;
    const int wid  = tid >> 6;

    if (blockIdx.x < UVBLK) {
        for (int i = tid; i < D * D; i += 256) {
            float wt = W_edge[i], wb = W_edge[D * D + i];
            Wu[i] = wt - wb;
            Wv[i] = wb;
        }

        // upfront x prefetch: 32 independent loads (clamped base, stores guarded)
        float xr[8][4];
#pragma unroll
        for (int g = 0; g < 8; ++g) {
            int n0 = blockIdx.x * UVNODES + wid * 32 + g * 4;
            int n0c = (n0 <= NN - 4) ? n0 : (NN - 4);
#pragma unroll
            for (int j = 0; j < 4; ++j)
                xr[g][j] = x[(size_t)(n0c + j) * D + lane];
        }
        __syncthreads();

        const float be = b_edge[lane];
#pragma unroll 1
        for (int g = 0; g < 8; ++g) {
            const int n0 = blockIdx.x * UVNODES + wid * 32 + g * 4;
#pragma unroll
            for (int j = 0; j < 4; ++j)
                xs[wid][lane][j] = xr[g][j];
            float au0 = be, au1 = be, au2 = be, au3 = be;
            float av0 = 0.f, av1 = 0.f, av2 = 0.f, av3 = 0.f;
#pragma unroll
            for (int k = 0; k < D; ++k) {
                f32x4 x4 = *(const f32x4*)&xs[wid][k][0];   // wave-uniform
                float wu = Wu[k * D + lane];
                float wv = Wv[k * D + lane];
                au0 += x4[0] * wu;  av0 += x4[0] * wv;
                au1 += x4[1] * wu;  av1 += x4[1] * wv;
                au2 += x4[2] * wu;  av2 += x4[2] * wv;
                au3 += x4[3] * wu;  av3 += x4[3] * wv;
            }
            if (n0 < NN) {   // n0 % 4 == 0 and NN % 4 == 0 -> all 4 valid
                u[(size_t)(n0 + 0) * D + lane] = f2bf(au0);
                u[(size_t)(n0 + 1) * D + lane] = f2bf(au1);
                u[(size_t)(n0 + 2) * D + lane] = f2bf(au2);
                u[(size_t)(n0 + 3) * D + lane] = f2bf(au3);
                v[(size_t)(n0 + 0) * D + lane] = f2bf(av0);
                v[(size_t)(n0 + 1) * D + lane] = f2bf(av1);
                v[(size_t)(n0 + 2) * D + lane] = f2bf(av2);
                v[(size_t)(n0 + 3) * D + lane] = f2bf(av3);
            }
        }
    } else {
        const int bb = blockIdx.x - UVBLK;
        if (bb == 0 && tid < 64)
            v[(size_t)NN * D + tid] = 0xFF80;           // sentinel row = -inf
        const int gtid = bb * 256 + tid;
        if (gtid * 4 < NE) {
            const int e0 = gtid * 4;
            const unsigned int sh = (unsigned int)(gtid & (NSHARD - 1));
            i32x4 s4 = *(const i32x4*)(ei + e0);
            i32x4 d4 = *(const i32x4*)(ei + NE + e0);
#pragma unroll
            for (int j = 0; j < 4; ++j) {
                unsigned int se = (unsigned int)s4[j];
                unsigned int de = (unsigned int)d4[j];
                unsigned int b  = (de >> 6) * NSHARD + sh;
                unsigned int pos = atomicAdd(&cursor[b * CSTRIDE], 1u);
                if (pos < SCAP)
                    bins[(size_t)b * SCAP + pos] = (se << 6) | (de & 63u);
            }
        }
    }
}

// ---------------------------------------------------------------------------
// slice (round-12 version, measured 75 us, VGPR 20, no spills):
// block owns dst rows [base, base+64). 512 threads = 8 waves.
// max_j relu(u+v_j) = relu(u + max_j v_j) -> u once per ROW.
//   1. local CSR: histogram + wave-0 prefix scan + scatter; lists padded
//      to x4 with sentinel src=NN (v[NN] = -inf).
//   2. per row (8 rows/wave): running register max over neighbor v-rows.
//      Per entry: 1 coalesced 128B gather + 1 v_max; indices via uniform
//      ds_read_b128 per 4 entries with next-chunk prefetch.
//   3. fused epilogue: out = relu(u+m) + x @ W_res + b_res (same wave).
// ---------------------------------------------------------------------------
__global__ __launch_bounds__(512) void slice_kernel(
    const float* __restrict__ x,
    const float* __restrict__ W_res,
    const float* __restrict__ b_res,
    const unsigned short* __restrict__ u,
    const unsigned short* __restrict__ v,
    const unsigned int* __restrict__ bins,
    const unsigned int* __restrict__ cursor,
    float* __restrict__ out)
{
    __shared__ float wres[D * D];      // 16 KB
    __shared__ int sorted[SCRTOT];     // 9.2 KB (src ids, CSR by row)
    __shared__ int cntL[64], ofsL[64], fillL[64];

    const int tid  = threadIdx.x;
    const int lane = tid & 63;
    const int wid  = tid >> 6;                 // 0..7
    const int base = blockIdx.x * SLICE;

    for (int i = tid; i < D * D; i += 512) wres[i] = W_res[i];
    if (tid < 64) { cntL[tid] = 0; fillL[tid] = 0; }
    __syncthreads();

    // ---- CSR build: histogram own shard (no-return ds_add) ----
    const unsigned int cidx = (unsigned int)blockIdx.x * NSHARD + wid;
    unsigned int cntS = cursor[cidx * CSTRIDE];
    if (cntS > SCAP) cntS = SCAP;
    const unsigned int* __restrict__ eb = bins + (size_t)cidx * SCAP;
    for (unsigned int i0 = lane; i0 < cntS; i0 += 64)
        atomicAdd(&cntL[eb[i0] & 63u], 1);
    __syncthreads();

    // ---- exclusive prefix scan of x4-rounded counts (wave 0) ----
    if (wid == 0) {
        int a = (cntL[lane] + 3) & ~3;
        int s = a;
#pragma unroll
        for (int off = 1; off < 64; off <<= 1) {
            int t = __shfl_up(s, off);
            if (lane >= off) s += t;
        }
        ofsL[lane] = s - a;
    }
    __syncthreads();

    // ---- scatter into CSR ----
    for (unsigned int i0 = lane; i0 < cntS; i0 += 64) {
        unsigned int e = eb[i0];
        int dl = (int)(e & 63u);
        int pos = ofsL[dl] + atomicAdd(&fillL[dl], 1);
        sorted[pos] = (int)(e >> 6);
    }
    __syncthreads();

    // ---- pad lists to x4 with sentinel (+4 tail for prefetch overread) ----
    if (tid < 64) {
        int c = cntL[tid], o = ofsL[tid];
        int a = (c + 3) & ~3;
        for (int j = c; j < a; ++j) sorted[o + j] = NN;
        if (tid == 63)
            for (int t = 0; t < 4; ++t) sorted[o + a + t] = NN;
    }
    __syncthreads();

    // ---- aggregate + epilogue: 8 rows per wave, lane = column ----
    const float br = b_res[lane];
#pragma unroll 1
    for (int i = 0; i < 8; ++i) {
        int r = wid * 8 + i;
        int n = base + r;
        if (n >= NN) break;
        float ur = b2f(u[(size_t)n * D + lane]);
        float xl = x[(size_t)n * D + lane];
        const int o = ofsL[r];
        const int a = (cntL[r] + 3) & ~3;
        float m = -__builtin_inff();
        i32x4 idx = *(const i32x4*)&sorted[o];          // uniform broadcast
#pragma unroll 2
        for (int j = 0; j < a; j += 4) {
            i32x4 nx = *(const i32x4*)&sorted[o + j + 4];  // prefetch
            float v0 = b2f(v[(size_t)idx[0] * D + lane]);
            float v1 = b2f(v[(size_t)idx[1] * D + lane]);
            float v2 = b2f(v[(size_t)idx[2] * D + lane]);
            float v3 = b2f(v[(size_t)idx[3] * D + lane]);
            m = fmaxf(m, fmaxf(fmaxf(v0, v1), fmaxf(v2, v3)));
            idx = nx;
        }
        float agg = fmaxf(0.f, ur + m);   // relu; empty row -> -inf -> 0
        float sr = br;
#pragma unroll
        for (int k = 0; k < D; ++k)
            sr += __shfl(xl, k) * wres[k * D + lane];
        out[(size_t)n * D + lane] = agg + sr;
    }
}

extern "C" void kernel_launch(void* const* d_in, const int* in_sizes, int n_in,
                              void* d_out, int out_size, void* d_ws, size_t ws_size,
                              hipStream_t stream) {
    const float* x      = (const float*)d_in[0];
    const int*   ei     = (const int*)d_in[1];
    const float* W_edge = (const float*)d_in[2];
    const float* b_edge = (const float*)d_in[3];
    const float* W_res  = (const float*)d_in[4];
    const float* b_res  = (const float*)d_in[5];
    float* out = (float*)d_out;

    // ws: cursor u32 (~512KB) | bins u32[NBLK*NSHARD*SCAP] (6.4MB)
    //     | u bf16[NN*D] (6.4MB) | v bf16[(NN+1)*D] (6.4MB + sentinel row)
    unsigned int*   cursor = (unsigned int*)d_ws;
    unsigned int*   bins   = (unsigned int*)((char*)d_ws + (1u << 19));
    unsigned short* uu     = (unsigned short*)((char*)d_ws + (1u << 19)
                              + (size_t)NBLK * NSHARD * SCAP * 4);
    unsigned short* vv     = uu + (size_t)NN * D;

    hipMemsetAsync(cursor, 0, NBLK * NSHARD * CSTRIDE * sizeof(unsigned int), stream);
    pre_fused<<<UVBLK + BINBLK, 256, 0, stream>>>(x, ei, W_edge, b_edge, uu, vv, bins, cursor);
    slice_kernel<<<NBLK, 512, 0, stream>>>(x, W_res, b_res, uu, vv, bins, cursor, out);
}